// Round 7
// baseline (117.202 us; speedup 1.0000x reference)
//
#include <hip/hip_runtime.h>
#include <hip/hip_bf16.h>

// PrototypicalNetwork: out[q,c] = -1/8 * sum_b sqrt(max(q2[q] + p2[b,c] - 2*qp[b,q,c], 0))
// bf16 MFMA 16x16x32 for qp GEMM (M=65536, N=1024, K=128).
// R7 = R6 + 64-row blocks with wave = 4mt x 2ct: B-frags reused across 4 m-tiles
// from registers -> pfrag L1/L2 traffic halves (512->256 MB device-wide), B-load
// and addressing instructions per output halve. R3 tried this shape but was
// confounded by IEEE sqrt (3x VALU) + 224 VGPR; this version keeps fast_sqrt,
// half-b ping-pong, per-group p2 loads to stay ~170 VGPR (3 waves/SIMD).

#define DIM   128
#define NCLS  128
#define SHOTS 32
#define NB    8
#define NQ    65536

using short8 = __attribute__((ext_vector_type(8))) short;
using f32x4  = __attribute__((ext_vector_type(4))) float;

__device__ __forceinline__ unsigned short f2bf(float x) {
  union { float f; unsigned u; } v; v.f = x;
  unsigned r = v.u + 0x7fffu + ((v.u >> 16) & 1u);   // RNE
  return (unsigned short)(r >> 16);
}

__device__ __forceinline__ short8 pack8_bf16(float4 a, float4 b) {
  // v_cvt_pk_bf16_f32 (gfx950, RNE): 4 insts per 8 elements
  __hip_bfloat162 p0 = __float22bfloat162_rn(make_float2(a.x, a.y));
  __hip_bfloat162 p1 = __float22bfloat162_rn(make_float2(a.z, a.w));
  __hip_bfloat162 p2 = __float22bfloat162_rn(make_float2(b.x, b.y));
  __hip_bfloat162 p3 = __float22bfloat162_rn(make_float2(b.z, b.w));
  union { __hip_bfloat162 h[4]; short8 s; } u;
  u.h[0] = p0; u.h[1] = p1; u.h[2] = p2; u.h[3] = p3;
  return u.s;
}

__device__ __forceinline__ float fast_sqrt(float x) {
#if __has_builtin(__builtin_amdgcn_sqrtf)
  return __builtin_amdgcn_sqrtf(x);   // raw v_sqrt_f32 (IEEE sqrtf was the R3 regression)
#else
  return sqrtf(x);
#endif
}

// ---------------------------------------------------------------------------
// Kernel 1: bootstrap-mean protos -> bf16(-proto/32) in MFMA B-frag-major
// layout, plus p2[b,c] = |proto|^2 / 64 (fp32).
// B-frag layout (16x16x32): lane holds B[n=lane&15][k=(lane>>4)*8+j].
// Slot = (b*8+ct)*4+kiter; one slot = 64 lanes * 16 B = 1 KB contiguous.
// ---------------------------------------------------------------------------
__global__ __launch_bounds__(128) void proto_kernel(
    const float* __restrict__ sup, const int* __restrict__ bidx,
    unsigned short* __restrict__ pfrag, float* __restrict__ p2) {
  int bc = blockIdx.x;            // b*128 + c
  int c  = bc & (NCLS - 1);
  int d  = threadIdx.x;           // 0..127 = feature dim
  __shared__ int   sidx[SHOTS];
  __shared__ float wsum[2];
  if (d < SHOTS) sidx[d] = bidx[bc * SHOTS + d];
  __syncthreads();
  float acc = 0.f;
  const float* base = sup + c * SHOTS * DIM + d;
  #pragma unroll
  for (int s = 0; s < SHOTS; ++s) acc += base[sidx[s] * DIM];
  float proto = acc * (1.0f / 32.0f);

  int b     = bc >> 7;
  int ct    = c >> 4, l15c = c & 15;
  int kiter = d >> 5, quad = (d >> 3) & 3, j = d & 7;
  int lane  = l15c + (quad << 4);
  int slot  = (b * 8 + ct) * 4 + kiter;
  pfrag[slot * 512 + lane * 8 + j] = f2bf(proto * -0.03125f);  // -proto/32

  float sq = proto * proto;
  #pragma unroll
  for (int off = 32; off > 0; off >>= 1) sq += __shfl_down(sq, off, 64);
  if ((d & 63) == 0) wsum[d >> 6] = sq;
  __syncthreads();
  if (d == 0) p2[bc] = (wsum[0] + wsum[1]) * (1.0f / 64.0f);
}

// ---------------------------------------------------------------------------
// Kernel 2: block = 64 query rows x 128 classes, 4 waves, grid 1024.
// Stage: 256 threads convert all 64 rows once (thread = (row, 32-float chunk)).
// Wave w holds ALL 4 m-tiles' A-frags in registers, owns c-tiles {2w, 2w+1}.
// b-loop: ping-pong at (b, ct) group granularity — 4 KB + p2 in flight.
// ---------------------------------------------------------------------------
#define SLOT_STRIDE 520   // 512 shorts payload + 8 pad

__global__ __launch_bounds__(256) void dist_kernel(
    const float* __restrict__ q, const uint4* __restrict__ pfrag,
    const float* __restrict__ p2, float* __restrict__ out) {
  int tid  = threadIdx.x;
  int w    = tid >> 6, lane = tid & 63;
  int l15  = lane & 15, quad = lane >> 4;
  int q0   = blockIdx.x << 6;

  __shared__ unsigned short aflds[16 * SLOT_STRIDE];  // slot = mt*4 + k
  __shared__ float q2s[64];                           // |q|^2 per row (unscaled)

  // --- staging: thread = (rloc = tid>>2, i = tid&3); converts 32 floats ---
  // A-frag: lane (m=l15, quad) of slot (mt, i) holds A[m][k=i*32+quad*8+j].
  {
    int rloc = tid >> 2;                 // 0..63 local row
    int i    = tid & 3;                  // k-iter (32-float chunk)
    const float* src = q + (size_t)(q0 + rloc) * DIM + i * 32;
    float4 x[8];
    #pragma unroll
    for (int v = 0; v < 8; ++v) x[v] = *reinterpret_cast<const float4*>(src + v * 4);
    float s = 0.f;
    #pragma unroll
    for (int v = 0; v < 8; ++v)
      s += x[v].x*x[v].x + x[v].y*x[v].y + x[v].z*x[v].z + x[v].w*x[v].w;
    s += __shfl_down(s, 2, 4);           // reduce the row's 4 chunks
    s += __shfl_down(s, 1, 4);
    if (i == 0) q2s[rloc] = s;

    int mt = rloc >> 4, m = rloc & 15;
    unsigned short* base = &aflds[(mt * 4 + i) * SLOT_STRIDE];
    #pragma unroll
    for (int qd = 0; qd < 4; ++qd)
      *reinterpret_cast<short8*>(&base[((qd << 4) + m) * 8]) =
          pack8_bf16(x[qd * 2], x[qd * 2 + 1]);
  }
  __syncthreads();

  // --- every wave pulls all 16 A-frags + q2' from LDS ---
  short8 af[4][4];
  #pragma unroll
  for (int mt = 0; mt < 4; ++mt)
    #pragma unroll
    for (int k = 0; k < 4; ++k)
      af[mt][k] = *reinterpret_cast<const short8*>(
          &aflds[(mt * 4 + k) * SLOT_STRIDE + lane * 8]);

  f32x4 q2r[4];                    // q2' for C/D row quad*4+r of each m-tile
  #pragma unroll
  for (int mt = 0; mt < 4; ++mt)
    #pragma unroll
    for (int r = 0; r < 4; ++r)
      q2r[mt][r] = q2s[mt * 16 + quad * 4 + r] * (1.0f / 64.0f);

  f32x4 oacc[4][2];
  #pragma unroll
  for (int mt = 0; mt < 4; ++mt)
    #pragma unroll
    for (int jj = 0; jj < 2; ++jj)
      oacc[mt][jj] = (f32x4){0.f, 0.f, 0.f, 0.f};

  // --- b-loop: 16 groups g = (b = g>>1, jj = g&1); X/Y register ping-pong ---
  uint4 bufX[4], bufY[4];
  float p2X, p2Y;

  #define LOAD_G(BUF, P2G, G)                                                 \
    {                                                                         \
      int b_ = (G) >> 1, ct_ = w * 2 + ((G) & 1);                             \
      const uint4* bp = pfrag + (size_t)((b_ * 8 + ct_) * 4) * 64 + lane;     \
      _Pragma("unroll")                                                       \
      for (int k = 0; k < 4; ++k) BUF[k] = bp[k * 64];                        \
      P2G = p2[b_ * NCLS + ct_ * 16 + l15];                                   \
    }

  #define COMPUTE_G(BUF, P2G, G)                                              \
    {                                                                         \
      int jj_ = (G) & 1;                                                      \
      f32x4 qp[4];                                                            \
      _Pragma("unroll")                                                       \
      for (int mt = 0; mt < 4; ++mt)                                          \
        _Pragma("unroll")                                                     \
        for (int r = 0; r < 4; ++r) qp[mt][r] = q2r[mt][r] + P2G;             \
      _Pragma("unroll")                                                       \
      for (int k = 0; k < 4; ++k) {                                           \
        short8 bfk = __builtin_bit_cast(short8, BUF[k]);                      \
        _Pragma("unroll")                                                     \
        for (int mt = 0; mt < 4; ++mt)                                        \
          qp[mt] = __builtin_amdgcn_mfma_f32_16x16x32_bf16(af[mt][k], bfk, qp[mt], 0, 0, 0); \
      }                                                                       \
      _Pragma("unroll")                                                       \
      for (int mt = 0; mt < 4; ++mt)                                          \
        _Pragma("unroll")                                                     \
        for (int r = 0; r < 4; ++r)                                           \
          oacc[mt][jj_][r] += fast_sqrt(fmaxf(qp[mt][r], 0.0f));              \
    }

  LOAD_G(bufX, p2X, 0)
  #pragma unroll 1
  for (int g = 0; g < 16; g += 2) {
    LOAD_G(bufY, p2Y, g + 1)             // in flight across X's compute
    COMPUTE_G(bufX, p2X, g)
    LOAD_G(bufX, p2X, (g + 2) & 15)      // wraps on last iter (harmless)
    COMPUTE_G(bufY, p2Y, g + 1)
  }
  #undef LOAD_G
  #undef COMPUTE_G

  // --- store: row = q0 + mt*16 + quad*4 + r, col = (2w+jj)*16 + l15 ---
  #pragma unroll
  for (int mt = 0; mt < 4; ++mt)
    #pragma unroll
    for (int jj = 0; jj < 2; ++jj) {
      int col = (w * 2 + jj) * 16 + l15;
      #pragma unroll
      for (int r = 0; r < 4; ++r) {
        int row = q0 + mt * 16 + quad * 4 + r;
        out[(size_t)row * NCLS + col] = -oacc[mt][jj][r];
      }
    }
}

extern "C" void kernel_launch(void* const* d_in, const int* in_sizes, int n_in,
                              void* d_out, int out_size, void* d_ws, size_t ws_size,
                              hipStream_t stream) {
  const float* sup   = (const float*)d_in[0];   // [4096,128] f32
  // d_in[1] = support_labels (unused: sorted/balanced by construction)
  const float* query = (const float*)d_in[2];   // [65536,128] f32
  const int*   bidx  = (const int*)d_in[3];     // [8,128,32] i32
  float* out = (float*)d_out;                   // [65536,128] f32

  unsigned short* pfrag = (unsigned short*)d_ws;              // 256 KB bf16 frags
  float* p2 = (float*)((char*)d_ws + (size_t)NB * NCLS * DIM * 2); // 4 KB

  proto_kernel<<<NB * NCLS, 128, 0, stream>>>(sup, bidx, pfrag, p2);
  dist_kernel<<<NQ / 64, 256, 0, stream>>>(query, (const uint4*)pfrag, p2, out);
}

// Round 8
// 113.056 us; speedup vs baseline: 1.0367x; 1.0367x over previous
//
#include <hip/hip_runtime.h>
#include <hip/hip_bf16.h>

// PrototypicalNetwork: out[q,c] = -1/8 * sum_b sqrt(max(q2[q] + p2[b,c] - 2*qp[b,q,c], 0))
// R8 = R6 shape (32x128 blocks, grid 2048, wave = 2mt x 2ct, ping-pong b-loop)
// with fp8 e4m3 fragments + mfma_f32_16x16x32_fp8_fp8 (bf16 rate, half the
// bytes): B-loads per b halve, pfrag traffic 512->256 MB, af regs halve.
// Only the cross term qp is fp8; q^2 and p^2 stay fp32. B = -p UNSCALED
// (p/32 would be e4m3-subnormal); C-init = (q^2+p^2)/2 so MFMA emits d^2/2;
// sqrt -> d/sqrt(2); sqrt(2)/8 folded into the store.

#define DIM   128
#define NCLS  128
#define SHOTS 32
#define NB    8
#define NQ    65536

using f32x4 = __attribute__((ext_vector_type(4))) float;

__device__ __forceinline__ float fast_sqrt(float x) {
#if __has_builtin(__builtin_amdgcn_sqrtf)
  return __builtin_amdgcn_sqrtf(x);   // raw v_sqrt_f32 (IEEE sqrtf = R3 regression)
#else
  return sqrtf(x);
#endif
}

__device__ __forceinline__ long u2l(unsigned x, unsigned y) {
  union { unsigned u[2]; long l; } v; v.u[0] = x; v.u[1] = y; return v.l;
}

// pack 4 floats -> 4 fp8 e4m3 bytes (one dword) via v_cvt_pk_fp8_f32
__device__ __forceinline__ unsigned pack4_fp8(float a, float b, float c, float d) {
  int r = 0;
  r = __builtin_amdgcn_cvt_pk_fp8_f32(a, b, r, false);  // low word
  r = __builtin_amdgcn_cvt_pk_fp8_f32(c, d, r, true);   // high word
  return (unsigned)r;
}

// ---------------------------------------------------------------------------
// Kernel 1: bootstrap-mean protos -> fp8(-proto) in MFMA B-frag-major layout,
// plus p2[b,c] = |proto|^2 / 2 (fp32).
// fp8 16x16x32 B-frag: lane (n=lane&15, quad=lane>>4) holds B[n][k=quad*8+j],
// 8 bytes. Two k-iters packed per 16 B: byte addr =
// ((b*8+ct)*2 + (kiter>>1))*1024 + lane*16 + (kiter&1)*8 + j.
// ---------------------------------------------------------------------------
__global__ __launch_bounds__(128) void proto_kernel(
    const float* __restrict__ sup, const int* __restrict__ bidx,
    unsigned char* __restrict__ pfrag, float* __restrict__ p2) {
  int bc = blockIdx.x;            // b*128 + c
  int c  = bc & (NCLS - 1);
  int d  = threadIdx.x;           // 0..127 = feature dim
  __shared__ int   sidx[SHOTS];
  __shared__ float wsum[2];
  if (d < SHOTS) sidx[d] = bidx[bc * SHOTS + d];
  __syncthreads();
  float acc = 0.f;
  const float* base = sup + c * SHOTS * DIM + d;
  #pragma unroll
  for (int s = 0; s < SHOTS; ++s) acc += base[sidx[s] * DIM];
  float proto = acc * (1.0f / 32.0f);

  int b     = bc >> 7;
  int ct    = c >> 4, l15c = c & 15;
  int kiter = d >> 5, quad = (d >> 3) & 3, j = d & 7;
  int lane  = l15c + (quad << 4);
  int addr  = ((b * 8 + ct) * 2 + (kiter >> 1)) * 1024 + lane * 16 + (kiter & 1) * 8 + j;
  int enc   = __builtin_amdgcn_cvt_pk_fp8_f32(-proto, -proto, 0, false);
  pfrag[addr] = (unsigned char)(enc & 0xff);

  float sq = proto * proto;
  #pragma unroll
  for (int off = 32; off > 0; off >>= 1) sq += __shfl_down(sq, off, 64);
  if ((d & 63) == 0) wsum[d >> 6] = sq;
  __syncthreads();
  if (d == 0) p2[bc] = (wsum[0] + wsum[1]) * 0.5f;
}

// ---------------------------------------------------------------------------
// Kernel 2: block = 32 query rows x 128 classes, 4 waves, grid 2048.
// Stage: wave w converts rows [8w, 8w+8) to fp8 A-frags in LDS (one cvt pass
// per block). Slots exactly 512 B (64 lanes x 8 B) — optimal bank spread for
// both b64 writes and b64 reads, no padding. Ping-pong b-loop, 2 c-tiles/wave.
// ---------------------------------------------------------------------------
__global__ __launch_bounds__(256) void dist_kernel(
    const float* __restrict__ q, const uint4* __restrict__ pfrag,
    const float* __restrict__ p2, float* __restrict__ out) {
  int tid  = threadIdx.x;
  int w    = tid >> 6, lane = tid & 63;
  int l15  = lane & 15, quad = lane >> 4;
  int q0   = blockIdx.x << 5;

  __shared__ unsigned char aflds[8 * 512];   // A-frags, slot = mt*4 + kiter
  __shared__ float q2s[32];                  // |q|^2 per row (unscaled)

  // --- staging: thread = (rloc = w*8 + lane>>3, chunk = lane&7), 16 floats ---
  // chunk c covers K [c*16, c*16+16): kiter i = c>>1, quads h*2, h*2+1 (h=c&1).
  {
    int rloc  = w * 8 + (lane >> 3);
    int chunk = lane & 7;
    const float* src = q + (size_t)(q0 + rloc) * DIM + chunk * 16;
    float4 x0 = *reinterpret_cast<const float4*>(src);
    float4 x1 = *reinterpret_cast<const float4*>(src + 4);
    float4 x2 = *reinterpret_cast<const float4*>(src + 8);
    float4 x3 = *reinterpret_cast<const float4*>(src + 12);
    float s = x0.x*x0.x + x0.y*x0.y + x0.z*x0.z + x0.w*x0.w
            + x1.x*x1.x + x1.y*x1.y + x1.z*x1.z + x1.w*x1.w
            + x2.x*x2.x + x2.y*x2.y + x2.z*x2.z + x2.w*x2.w
            + x3.x*x3.x + x3.y*x3.y + x3.z*x3.z + x3.w*x3.w;
    s += __shfl_down(s, 4, 8);
    s += __shfl_down(s, 2, 8);
    s += __shfl_down(s, 1, 8);
    if (chunk == 0) q2s[rloc] = s;

    int mt = rloc >> 4, m = rloc & 15, i = chunk >> 1, h = chunk & 1;
    unsigned char* bse = &aflds[(mt * 4 + i) * 512];
    uint2 g0, g1;
    g0.x = pack4_fp8(x0.x, x0.y, x0.z, x0.w);
    g0.y = pack4_fp8(x1.x, x1.y, x1.z, x1.w);
    g1.x = pack4_fp8(x2.x, x2.y, x2.z, x2.w);
    g1.y = pack4_fp8(x3.x, x3.y, x3.z, x3.w);
    *reinterpret_cast<uint2*>(&bse[(((h * 2 + 0) << 4) + m) * 8]) = g0;
    *reinterpret_cast<uint2*>(&bse[(((h * 2 + 1) << 4) + m) * 8]) = g1;
  }
  __syncthreads();

  // --- every wave pulls all 8 A-frags (2mt x 4k, 8 B each) + q2' from LDS ---
  long af[2][4];
  #pragma unroll
  for (int mt = 0; mt < 2; ++mt)
    #pragma unroll
    for (int k = 0; k < 4; ++k)
      af[mt][k] = *reinterpret_cast<const long*>(
          &aflds[(mt * 4 + k) * 512 + lane * 8]);

  f32x4 q2r[2];                    // q^2/2 for C/D row quad*4+r of each m-tile
  #pragma unroll
  for (int mt = 0; mt < 2; ++mt)
    #pragma unroll
    for (int r = 0; r < 4; ++r)
      q2r[mt][r] = q2s[mt * 16 + quad * 4 + r] * 0.5f;

  // p2' (= |p|^2/2) hoisted for this wave's two c-tiles, all b
  float p2v[NB][2];
  #pragma unroll
  for (int b = 0; b < NB; ++b)
    #pragma unroll
    for (int jj = 0; jj < 2; ++jj)
      p2v[b][jj] = p2[b * NCLS + (w * 2 + jj) * 16 + l15];

  f32x4 oacc[2][2];
  #pragma unroll
  for (int i = 0; i < 2; ++i)
    #pragma unroll
    for (int jj = 0; jj < 2; ++jj)
      oacc[i][jj] = (f32x4){0.f, 0.f, 0.f, 0.f};

  // --- b-loop: X/Y ping-pong; 4 b128 loads (2 ct x 2 pairs) in flight ---
  uint4 bufX[4], bufY[4];

  #define LOAD_B(BUF, B)                                                      \
    {                                                                         \
      _Pragma("unroll")                                                       \
      for (int jj = 0; jj < 2; ++jj) {                                        \
        int ct = w * 2 + jj;                                                  \
        const uint4* bp = pfrag + (size_t)(((B) * 8 + ct) * 2) * 64 + lane;   \
        BUF[jj * 2 + 0] = bp[0];                                              \
        BUF[jj * 2 + 1] = bp[64];                                             \
      }                                                                       \
    }

  #define COMPUTE_B(BUF, B)                                                   \
    {                                                                         \
      _Pragma("unroll")                                                       \
      for (int jj = 0; jj < 2; ++jj) {                                        \
        long b0 = u2l(BUF[jj * 2 + 0].x, BUF[jj * 2 + 0].y);                  \
        long b1 = u2l(BUF[jj * 2 + 0].z, BUF[jj * 2 + 0].w);                  \
        long b2 = u2l(BUF[jj * 2 + 1].x, BUF[jj * 2 + 1].y);                  \
        long b3 = u2l(BUF[jj * 2 + 1].z, BUF[jj * 2 + 1].w);                  \
        f32x4 qp0, qp1;                                                       \
        _Pragma("unroll")                                                     \
        for (int r = 0; r < 4; ++r) {                                         \
          qp0[r] = q2r[0][r] + p2v[B][jj];                                    \
          qp1[r] = q2r[1][r] + p2v[B][jj];                                    \
        }                                                                     \
        qp0 = __builtin_amdgcn_mfma_f32_16x16x32_fp8_fp8(af[0][0], b0, qp0, 0, 0, 0); \
        qp1 = __builtin_amdgcn_mfma_f32_16x16x32_fp8_fp8(af[1][0], b0, qp1, 0, 0, 0); \
        qp0 = __builtin_amdgcn_mfma_f32_16x16x32_fp8_fp8(af[0][1], b1, qp0, 0, 0, 0); \
        qp1 = __builtin_amdgcn_mfma_f32_16x16x32_fp8_fp8(af[1][1], b1, qp1, 0, 0, 0); \
        qp0 = __builtin_amdgcn_mfma_f32_16x16x32_fp8_fp8(af[0][2], b2, qp0, 0, 0, 0); \
        qp1 = __builtin_amdgcn_mfma_f32_16x16x32_fp8_fp8(af[1][2], b2, qp1, 0, 0, 0); \
        qp0 = __builtin_amdgcn_mfma_f32_16x16x32_fp8_fp8(af[0][3], b3, qp0, 0, 0, 0); \
        qp1 = __builtin_amdgcn_mfma_f32_16x16x32_fp8_fp8(af[1][3], b3, qp1, 0, 0, 0); \
        _Pragma("unroll")                                                     \
        for (int r = 0; r < 4; ++r) {                                         \
          oacc[0][jj][r] += fast_sqrt(fmaxf(qp0[r], 0.0f));                   \
          oacc[1][jj][r] += fast_sqrt(fmaxf(qp1[r], 0.0f));                   \
        }                                                                     \
      }                                                                       \
    }

  LOAD_B(bufX, 0)
  #pragma unroll 1
  for (int i = 0; i < NB; i += 2) {
    LOAD_B(bufY, i + 1)                 // in flight across X's compute
    COMPUTE_B(bufX, i)
    LOAD_B(bufX, (i + 2) & (NB - 1))    // wraps on last iter (harmless)
    COMPUTE_B(bufY, i + 1)
  }
  #undef LOAD_B
  #undef COMPUTE_B

  // --- store: oacc holds sum_b d/sqrt(2); out = -(sqrt(2)/8) * oacc ---
  #pragma unroll
  for (int mt2 = 0; mt2 < 2; ++mt2)
    #pragma unroll
    for (int jj = 0; jj < 2; ++jj) {
      int col = (w * 2 + jj) * 16 + l15;
      #pragma unroll
      for (int r = 0; r < 4; ++r) {
        int row = q0 + mt2 * 16 + quad * 4 + r;
        out[(size_t)row * NCLS + col] = -0.17677669529663689f * oacc[mt2][jj][r];
      }
    }
}

extern "C" void kernel_launch(void* const* d_in, const int* in_sizes, int n_in,
                              void* d_out, int out_size, void* d_ws, size_t ws_size,
                              hipStream_t stream) {
  const float* sup   = (const float*)d_in[0];   // [4096,128] f32
  // d_in[1] = support_labels (unused: sorted/balanced by construction)
  const float* query = (const float*)d_in[2];   // [65536,128] f32
  const int*   bidx  = (const int*)d_in[3];     // [8,128,32] i32
  float* out = (float*)d_out;                   // [65536,128] f32

  unsigned char* pfrag = (unsigned char*)d_ws;            // 128 KB fp8 frags
  float* p2 = (float*)((char*)d_ws + 256 * 1024);         // same offset as R6/R7

  proto_kernel<<<NB * NCLS, 128, 0, stream>>>(sup, bidx, pfrag, p2);
  dist_kernel<<<NQ / 32, 256, 0, stream>>>(query, (const uint4*)pfrag, p2, out);
}